// Round 1
// baseline (250.024 us; speedup 1.0000x reference)
//
#include <hip/hip_runtime.h>
#include <math.h>

#define B_ 4
#define N_ 2048
#define C_ 64
#define K_ 32
#define BN_ (B_ * N_)  // 8192

// ws float layout
// [0, 8192)        sums -> means (B*K*C), zeroed by k_zero
// [8192, 8320)     counts (B*K), zeroed
// [8320, 8324)     accum: 0=anchor_sum 1=mask_cnt 2=nll_sum, zeroed
// [8448, 16640)    invn (BN)  (fully overwritten)
// [16640, 213248)  part (BN * 24) (fully overwritten)
#define WS_SUMS 0
#define WS_COUNTS 8192
#define WS_ACCUM 8320
#define WS_INVN 8448
#define WS_PART 16640

__global__ void k_zero(float* __restrict__ ws) {
  int i = blockIdx.x * 256 + threadIdx.x;
  if (i < 8324) ws[i] = 0.0f;
}

// One wave per row: normalize contr_emb row, atomic cluster sums + counts,
// store 1/norm for reuse by k_logits.
__global__ __launch_bounds__(256) void k_norm_cluster(
    const float* __restrict__ contr, const int* __restrict__ labels,
    float* __restrict__ ws) {
  int gid = blockIdx.x * 256 + threadIdx.x;
  int row = gid >> 6;            // [0, BN)
  int lane = threadIdx.x & 63;
  float x = contr[row * C_ + lane];
  float ss = x * x;
#pragma unroll
  for (int off = 32; off > 0; off >>= 1) ss += __shfl_xor(ss, off);
  float inv = 1.0f / fmaxf(sqrtf(ss), 1e-12f);
  float c = x * inv;
  int b = row >> 11;             // row / N
  int lbl = labels[row];         // [0, K)
  atomicAdd(&ws[WS_SUMS + (b * K_ + lbl) * C_ + lane], c);
  if (lane == 0) {
    atomicAdd(&ws[WS_COUNTS + b * K_ + lbl], 1.0f);
    ws[WS_INVN + row] = inv;
  }
}

__global__ void k_means(float* __restrict__ ws) {
  int i = blockIdx.x * 256 + threadIdx.x;  // 8192 = B*K*C
  ws[WS_SUMS + i] /= fmaxf(ws[WS_COUNTS + (i >> 6)], 1.0f);
}

// grid (BN/64, 8): block = 1 wave = 64 rows (row on lane), 16 cols per block
// (cols uniform via blockIdx.y -> means loads are wave-uniform / scalar-cached).
// Emits per-(row, colgroup) partial (max, sumexp, target_logit_or_-inf).
__global__ __launch_bounds__(64) void k_logits(
    const float* __restrict__ contr, const int* __restrict__ labels,
    const float* __restrict__ ws, float* __restrict__ part) {
  __shared__ float crow[64 * 65];  // stride 65: (row + k) % 32 banks -> 2-way max
  int t = threadIdx.x;
  int rowbase = blockIdx.x * 64;
  const float4* c4 = (const float4*)(contr + rowbase * C_);
  const float* invn = ws + WS_INVN;
  for (int ii = t; ii < 1024; ii += 64) {  // 64 rows * 16 float4
    int r = ii >> 4, q = ii & 15;
    float4 v = c4[ii];
    float inv = invn[rowbase + r];
    int base = r * 65 + q * 4;
    crow[base + 0] = v.x * inv;
    crow[base + 1] = v.y * inv;
    crow[base + 2] = v.z * inv;
    crow[base + 3] = v.w * inv;
  }
  __syncthreads();
  const float* means = ws + WS_SUMS;
  int g16 = blockIdx.y * 16;
  float acc[16];
#pragma unroll
  for (int j = 0; j < 16; ++j) acc[j] = 0.0f;
#pragma unroll 4
  for (int k = 0; k < 64; ++k) {
    float ck = crow[t * 65 + k];
#pragma unroll
    for (int j = 0; j < 16; ++j) acc[j] += ck * means[(g16 + j) * C_ + k];
  }
  int row = rowbase + t;
  int tgt = labels[row];
  float m = -1e30f, tl = -1e30f;
#pragma unroll
  for (int j = 0; j < 16; ++j) {
    m = fmaxf(m, acc[j]);
    tl = (g16 + j == tgt) ? acc[j] : tl;
  }
  float s = 0.0f;
#pragma unroll
  for (int j = 0; j < 16; ++j) s += __expf(acc[j] - m);
  float* p = part + row * 24 + blockIdx.y * 3;
  p[0] = m;
  p[1] = s;
  p[2] = tl;
}

// Combine 8 colgroup partials per row -> nll, atomic sum.
__global__ __launch_bounds__(256) void k_nll(
    const float* __restrict__ part, float* __restrict__ ws) {
  int row = blockIdx.x * 256 + threadIdx.x;  // 8192
  const float* p = part + row * 24;
  float m = -1e30f;
#pragma unroll
  for (int g = 0; g < 8; ++g) m = fmaxf(m, p[g * 3]);
  float s = 0.0f, tl = -1e30f;
#pragma unroll
  for (int g = 0; g < 8; ++g) {
    s += p[g * 3 + 1] * __expf(p[g * 3] - m);
    tl = fmaxf(tl, p[g * 3 + 2]);
  }
  float nll = (m + logf(s)) - tl;
#pragma unroll
  for (int off = 32; off > 0; off >>= 1) nll += __shfl_xor(nll, off);
  if ((threadIdx.x & 63) == 0) atomicAdd(&ws[WS_ACCUM + 2], nll);
}

// Anchor term: s = emb + abs_coords staged in LDS (SoA -> conflict-free float4
// reads), mask streamed as int4 (HBM-bound, 67 MB). 8 rows per block.
__global__ __launch_bounds__(256) void k_anchor(
    const float* __restrict__ emb, const float* __restrict__ abscoord,
    const int* __restrict__ mask, float* __restrict__ ws) {
  __shared__ float sx[N_], sy[N_];
  int b = blockIdx.x >> 8;       // 256 blocks per batch
  int rb = blockIdx.x & 255;
  int t = threadIdx.x;
  const float2* e2 = (const float2*)(emb + b * N_ * 2);
  const float2* a2 = (const float2*)(abscoord + b * N_ * 2);
  for (int i = t; i < N_; i += 256) {
    float2 ev = e2[i], av = a2[i];
    sx[i] = ev.x + av.x;
    sy[i] = ev.y + av.y;
  }
  __syncthreads();
  const float4* sx4 = (const float4*)sx;
  const float4* sy4 = (const float4*)sy;
  float acc = 0.0f, cnt = 0.0f;
  for (int r = 0; r < 8; ++r) {
    int i = rb * 8 + r;
    float six = sx[i], siy = sy[i];
    const int4* mrow = (const int4*)(mask + (size_t)(b * N_ + i) * N_);
    for (int jj = t; jj < N_ / 4; jj += 256) {
      int4 mv = mrow[jj];
      float4 xs = sx4[jj], ys = sy4[jj];
      float dx, dy, d2, v;
      dx = six - xs.x; dy = siy - ys.x; d2 = dx * dx + dy * dy;
      v = 1.0f - __expf(d2 * -0.1f);
      if (mv.x == 1) { acc += v; cnt += 1.0f; }
      dx = six - xs.y; dy = siy - ys.y; d2 = dx * dx + dy * dy;
      v = 1.0f - __expf(d2 * -0.1f);
      if (mv.y == 1) { acc += v; cnt += 1.0f; }
      dx = six - xs.z; dy = siy - ys.z; d2 = dx * dx + dy * dy;
      v = 1.0f - __expf(d2 * -0.1f);
      if (mv.z == 1) { acc += v; cnt += 1.0f; }
      dx = six - xs.w; dy = siy - ys.w; d2 = dx * dx + dy * dy;
      v = 1.0f - __expf(d2 * -0.1f);
      if (mv.w == 1) { acc += v; cnt += 1.0f; }
    }
  }
#pragma unroll
  for (int off = 32; off > 0; off >>= 1) {
    acc += __shfl_xor(acc, off);
    cnt += __shfl_xor(cnt, off);
  }
  if ((t & 63) == 0) {
    atomicAdd(&ws[WS_ACCUM + 0], acc);
    atomicAdd(&ws[WS_ACCUM + 1], cnt);
  }
}

__global__ void k_final(const float* __restrict__ ws, float* __restrict__ out) {
  out[0] = ws[WS_ACCUM + 0] / ws[WS_ACCUM + 1] +
           10.0f * ws[WS_ACCUM + 2] * (1.0f / (float)BN_);
}

extern "C" void kernel_launch(void* const* d_in, const int* in_sizes, int n_in,
                              void* d_out, int out_size, void* d_ws, size_t ws_size,
                              hipStream_t stream) {
  const float* emb    = (const float*)d_in[0];
  const float* contr  = (const float*)d_in[1];
  const float* absc   = (const float*)d_in[2];
  const int*   mask   = (const int*)d_in[3];
  const int*   labels = (const int*)d_in[4];
  float* ws  = (float*)d_ws;
  float* out = (float*)d_out;
  float* part = ws + WS_PART;

  k_zero<<<33, 256, 0, stream>>>(ws);
  k_norm_cluster<<<BN_ * 64 / 256, 256, 0, stream>>>(contr, labels, ws);
  k_means<<<32, 256, 0, stream>>>(ws);
  k_logits<<<dim3(BN_ / 64, 8), 64, 0, stream>>>(contr, labels, ws, part);
  k_nll<<<BN_ / 256, 256, 0, stream>>>(part, ws);
  k_anchor<<<B_ * 256, 256, 0, stream>>>(emb, absc, mask, ws);
  k_final<<<1, 1, 0, stream>>>(ws, out);
}